// Round 4
// baseline (270.553 us; speedup 1.0000x reference)
//
#include <hip/hip_runtime.h>
#include <math.h>

#define L_ 2048
#define D_ 512
#define K_ 64
#define GRP 4

typedef __attribute__((ext_vector_type(8))) short short8;
typedef __attribute__((ext_vector_type(4))) float f32x4;
typedef __attribute__((ext_vector_type(4))) unsigned short us4;
typedef __attribute__((ext_vector_type(8))) unsigned short us8;

__device__ __forceinline__ unsigned short f2bf(float f) {
    unsigned int u = __builtin_bit_cast(unsigned int, f);
    u += 0x7fffu + ((u >> 16) & 1u);   // RNE
    return (unsigned short)(u >> 16);
}
__device__ __forceinline__ float bf2f(unsigned int u) {
    return __builtin_bit_cast(float, u << 16);
}
__device__ __forceinline__ f32x4 MFMA(short8 a, short8 b, f32x4 c) {
    return __builtin_amdgcn_mfma_f32_16x16x32_bf16(a, b, c, 0, 0, 0);
}

enum { EPI_BIAS = 0, EPI_GELU = 1, EPI_AMP = 2, EPI_OUT = 4 };

// ---------- pipelined bf16 MFMA GEMM body: 64x64 tile, BK=64, dbuf LDS ----------
template<int EPI>
__device__ __forceinline__ void gemm_body(
    const unsigned short* __restrict__ A, const unsigned short* __restrict__ Bt,
    const float* __restrict__ bias, int N, int Kd, int m0, int n0,
    unsigned short* __restrict__ Cb, float* __restrict__ Cf,
    const float* __restrict__ extra,
    unsigned short* As, unsigned short* Bs)      // each 2*64*72
{
    const int t = threadIdx.x;
    const int w = t >> 6, lane = t & 63, n_ = lane & 15, quad = lane >> 4;
    const int mh = (w >> 1) * 32, nh = (w & 1) * 32;

    f32x4 acc[2][2];
#pragma unroll
    for (int i = 0; i < 2; i++)
#pragma unroll
        for (int j = 0; j < 2; j++) acc[i][j] = (f32x4){0.f, 0.f, 0.f, 0.f};

    const int sr = t >> 2, sseg = (t & 3) * 16;
    const unsigned short* Ap = &A[(size_t)(m0 + sr) * Kd + sseg];
    const unsigned short* Bp = &Bt[(size_t)(n0 + sr) * Kd + sseg];
    const int swoff = sr * 72 + sseg;

    short8 av0 = *(const short8*)(Ap);
    short8 av1 = *(const short8*)(Ap + 8);
    short8 bv0 = *(const short8*)(Bp);
    short8 bv1 = *(const short8*)(Bp + 8);

    int buf = 0;
    *(short8*)(As + swoff) = av0; *(short8*)(As + swoff + 8) = av1;
    *(short8*)(Bs + swoff) = bv0; *(short8*)(Bs + swoff + 8) = bv1;
    __syncthreads();

    for (int k0 = 0; k0 < Kd; k0 += 64) {
        const bool more = (k0 + 64 < Kd);
        if (more) {
            av0 = *(const short8*)(Ap + k0 + 64);
            av1 = *(const short8*)(Ap + k0 + 72);
            bv0 = *(const short8*)(Bp + k0 + 64);
            bv1 = *(const short8*)(Bp + k0 + 72);
        }
        const unsigned short* Ab = As + buf * 4608;
        const unsigned short* Bb = Bs + buf * 4608;
#pragma unroll
        for (int kc = 0; kc < 2; kc++) {
            short8 a0 = *(const short8*)&Ab[(mh      + n_) * 72 + kc * 32 + quad * 8];
            short8 a1 = *(const short8*)&Ab[(mh + 16 + n_) * 72 + kc * 32 + quad * 8];
            short8 b0 = *(const short8*)&Bb[(nh      + n_) * 72 + kc * 32 + quad * 8];
            short8 b1 = *(const short8*)&Bb[(nh + 16 + n_) * 72 + kc * 32 + quad * 8];
            acc[0][0] = MFMA(a0, b0, acc[0][0]);
            acc[0][1] = MFMA(a0, b1, acc[0][1]);
            acc[1][0] = MFMA(a1, b0, acc[1][0]);
            acc[1][1] = MFMA(a1, b1, acc[1][1]);
        }
        if (more) {
            buf ^= 1;
            unsigned short* Aw = As + buf * 4608 + swoff;
            unsigned short* Bw = Bs + buf * 4608 + swoff;
            *(short8*)Aw = av0; *(short8*)(Aw + 8) = av1;
            *(short8*)Bw = bv0; *(short8*)(Bw + 8) = bv1;
            __syncthreads();
        }
    }

#pragma unroll
    for (int i = 0; i < 2; i++) {
#pragma unroll
        for (int j = 0; j < 2; j++) {
            const int mb = m0 + mh + i * 16 + quad * 4;
            const int nb = n0 + nh + j * 16 + n_;
            const float bsv = bias[nb];
#pragma unroll
            for (int reg = 0; reg < 4; reg++) {
                const int m = mb + reg;
                float v = acc[i][j][reg] + bsv;
                if (EPI == EPI_GELU) {
                    v = 0.5f * v * (1.0f + erff(v * 0.70710678118654752f));
                    Cb[(size_t)m * N + nb] = f2bf(v);
                } else if (EPI == EPI_BIAS) {
                    Cb[(size_t)m * N + nb] = f2bf(v);
                } else if (EPI == EPI_AMP) {
                    float u = (v > 20.f) ? v : log1pf(expf(v));
                    Cf[(size_t)m * N + nb] = u + 0.1f;
                } else { // EPI_OUT
                    Cf[(size_t)m * N + nb] = v + extra[(size_t)m * N + nb];
                }
            }
        }
    }
}

// ---------- phase GEMM body: 32x64 tile (N=64, Kd=512), dbuf, phase epilogue ----------
__device__ __forceinline__ void phase_body(
    const unsigned short* __restrict__ A, const unsigned short* __restrict__ Bt,
    const float* __restrict__ bias, int m0,
    unsigned short* __restrict__ Cb, const float* __restrict__ amp,
    unsigned short* As, unsigned short* Bs)   // As: 2*32*72, Bs: 2*64*72
{
    const int t = threadIdx.x;
    const int w = t >> 6, lane = t & 63, n_ = lane & 15, quad = lane >> 4;
    const int Kd = 512;

    f32x4 acc[2];
    acc[0] = (f32x4){0.f, 0.f, 0.f, 0.f};
    acc[1] = (f32x4){0.f, 0.f, 0.f, 0.f};

    const int arow = t >> 3, aseg = (t & 7) * 8;      // A: 32x64
    const int brow = t >> 2, bseg = (t & 3) * 16;     // B: 64x64
    const unsigned short* Ap = &A[(size_t)(m0 + arow) * Kd + aseg];
    const unsigned short* Bp = &Bt[(size_t)brow * Kd + bseg];
    const int aoff = arow * 72 + aseg;
    const int boff = brow * 72 + bseg;

    short8 av  = *(const short8*)Ap;
    short8 bv0 = *(const short8*)Bp;
    short8 bv1 = *(const short8*)(Bp + 8);

    int buf = 0;
    *(short8*)(As + aoff) = av;
    *(short8*)(Bs + boff) = bv0; *(short8*)(Bs + boff + 8) = bv1;
    __syncthreads();

    for (int k0 = 0; k0 < Kd; k0 += 64) {
        const bool more = (k0 + 64 < Kd);
        if (more) {
            av  = *(const short8*)(Ap + k0 + 64);
            bv0 = *(const short8*)(Bp + k0 + 64);
            bv1 = *(const short8*)(Bp + k0 + 72);
        }
        const unsigned short* Ab = As + buf * 2304;
        const unsigned short* Bb = Bs + buf * 4608;
#pragma unroll
        for (int kc = 0; kc < 2; kc++) {
            short8 a0 = *(const short8*)&Ab[(n_)      * 72 + kc * 32 + quad * 8];
            short8 a1 = *(const short8*)&Ab[(16 + n_) * 72 + kc * 32 + quad * 8];
            short8 b0 = *(const short8*)&Bb[(w * 16 + n_) * 72 + kc * 32 + quad * 8];
            acc[0] = MFMA(a0, b0, acc[0]);
            acc[1] = MFMA(a1, b0, acc[1]);
        }
        if (more) {
            buf ^= 1;
            *(short8*)(As + buf * 2304 + aoff) = av;
            *(short8*)(Bs + buf * 4608 + boff) = bv0;
            *(short8*)(Bs + buf * 4608 + boff + 8) = bv1;
            __syncthreads();
        }
    }

    const int nb = w * 16 + n_;
    const float bsv = bias[nb];
#pragma unroll
    for (int i = 0; i < 2; i++) {
        const int mb = m0 + i * 16 + quad * 4;
#pragma unroll
        for (int reg = 0; reg < 4; reg++) {
            const int m = mb + reg;
            float v = acc[i][reg] + bsv;
            float am = amp[(size_t)m * 64 + nb];
            float p = tanhf(v) * 3.14159265358979323846f;
            float sp, cp; sincosf(p, &sp, &cp);
            Cb[(size_t)m * 128 + nb]      = f2bf(am * cp);
            Cb[(size_t)m * 128 + 64 + nb] = f2bf(am * sp);
        }
    }
}

// ---------- prep: weight transpose+cast (z<7), x cast + counter zero (z=7) ----------
__global__ __launch_bounds__(256)
void prep_k(const float* x, unsigned short* xb, int* cnt,
            const float* s0, const float* s1, const float* s2, const float* s3,
            const float* s4, const float* s5, const float* s6,
            unsigned short* d0, unsigned short* d1, unsigned short* d2, unsigned short* d3,
            unsigned short* d4, unsigned short* d5, unsigned short* d6)
{
    const int t = threadIdx.x;
    if (blockIdx.z == 7) {
        if (blockIdx.x == 0 && blockIdx.y == 0 && t < 64) cnt[t] = 0;
        const int b = blockIdx.y * 16 + blockIdx.x;       // 0..255
        const float4* src = (const float4*)x;
#pragma unroll
        for (int j = 0; j < 4; j++) {
            const int idx = b * 1024 + j * 256 + t;
            float4 v = src[idx];
            us4 o;
            o.x = f2bf(v.x); o.y = f2bf(v.y); o.z = f2bf(v.z); o.w = f2bf(v.w);
            *(us4*)&xb[(size_t)idx * 4] = o;
        }
        return;
    }
    const float* S; unsigned short* D; int C;
    switch (blockIdx.z) {
        case 0: S = s0; D = d0; C = 512; break;
        case 1: S = s1; D = d1; C = 512; break;
        case 2: S = s2; D = d2; C = 512; break;
        case 3: S = s3; D = d3; C = 512; break;
        case 4: S = s4; D = d4; C = 64;  break;
        case 5: S = s5; D = d5; C = 64;  break;
        default: S = s6; D = d6; C = 64; break;
    }
    const int R = 512;
    int c0 = blockIdx.x * 32, r0 = blockIdx.y * 32;
    if (c0 >= C) return;
    __shared__ float tile[32][33];
    int r = t >> 3, c4 = (t & 7) * 4;
    float4 v = *(const float4*)&S[(size_t)(r0 + r) * C + c0 + c4];
    tile[r][c4 + 0] = v.x; tile[r][c4 + 1] = v.y;
    tile[r][c4 + 2] = v.z; tile[r][c4 + 3] = v.w;
    __syncthreads();
    us4 o;
    o.x = f2bf(tile[c4 + 0][r]); o.y = f2bf(tile[c4 + 1][r]);
    o.z = f2bf(tile[c4 + 2][r]); o.w = f2bf(tile[c4 + 3][r]);
    *(us4*)&D[(size_t)(c0 + r) * R + r0 + c4] = o;
}

// ---------- fused ke1+qe1+v+amp GEMMs; bid = which*256 + n*32 + m  (XCD A-locality) ----
__global__ __launch_bounds__(256)
void qkva_k(const unsigned short* __restrict__ xb,
            const unsigned short* wtke1, const unsigned short* wtqe1,
            const unsigned short* wtv, const unsigned short* wtamp,
            const float* ke_b1, const float* qe_b1, const float* v_b, const float* amp_b,
            unsigned short* hk, unsigned short* hq, unsigned short* Vb, float* amp)
{
    __shared__ unsigned short As[2 * 4608];
    __shared__ unsigned short Bs[2 * 4608];
    const int b = blockIdx.x;
    if (b < 768) {
        const int which = b >> 8, wi = b & 255;
        const int m0 = (wi & 31) * 64, n0 = (wi >> 5) * 64;
        if (which == 0)
            gemm_body<EPI_GELU>(xb, wtke1, ke_b1, 512, 512, m0, n0, hk, nullptr, nullptr, As, Bs);
        else if (which == 1)
            gemm_body<EPI_GELU>(xb, wtqe1, qe_b1, 512, 512, m0, n0, hq, nullptr, nullptr, As, Bs);
        else
            gemm_body<EPI_BIAS>(xb, wtv, v_b, 512, 512, m0, n0, Vb, nullptr, nullptr, As, Bs);
    } else {
        const int m0 = (b - 768) * 64;
        gemm_body<EPI_AMP>(xb, wtamp, amp_b, 64, 512, m0, 0, nullptr, amp, nullptr, As, Bs);
    }
}

// ---------- fused phase GEMMs (128 blocks of 32x64) + V transpose ----------
__global__ __launch_bounds__(256)
void phtv_k(const unsigned short* __restrict__ hk, const unsigned short* __restrict__ hq,
            const unsigned short* wtke2, const unsigned short* wtqe2,
            const float* ke_b2, const float* qe_b2, const float* ampv,
            unsigned short* Kp, unsigned short* Qp,
            const unsigned short* __restrict__ Vb, unsigned short* __restrict__ Vt)
{
    __shared__ unsigned short As[2 * 2304];
    __shared__ unsigned short Bs[2 * 4608];
    const int b = blockIdx.x;
    if (b < 128) {
        if (b < 64)
            phase_body(hk, wtke2, ke_b2, b * 32, Kp, ampv, As, Bs);
        else
            phase_body(hq, wtqe2, qe_b2, (b - 64) * 32, Qp, ampv, As, Bs);
    } else {
        const int bb = b - 128;
        const int c0 = (bb & 15) * 32, r0 = (bb >> 4) * 32;
        unsigned short (*tile)[33] = (unsigned short (*)[33])As;
        const int t = threadIdx.x, r = t >> 3, c4 = (t & 7) * 4;
        us4 v = *(const us4*)&Vb[(size_t)(r0 + r) * 512 + c0 + c4];
        tile[r][c4 + 0] = v.x; tile[r][c4 + 1] = v.y;
        tile[r][c4 + 2] = v.z; tile[r][c4 + 3] = v.w;
        __syncthreads();
        us4 o;
        o.x = tile[c4 + 0][r]; o.y = tile[c4 + 1][r];
        o.z = tile[c4 + 2][r]; o.w = tile[c4 + 3][r];
        *(us4*)&Vt[(size_t)(c0 + r) * 2048 + r0 + c4] = o;
    }
}

// ---------- MFMA causal attention, 4 tiles per barrier pair, fused redln ----------
__global__ __launch_bounds__(256)
void attm_k(const unsigned short* __restrict__ Qp, const unsigned short* __restrict__ Kp,
            const unsigned short* __restrict__ Vt, unsigned short* __restrict__ P, int ng,
            int* __restrict__ cnt, const float* __restrict__ lng, const float* __restrict__ lnb,
            unsigned short* __restrict__ rnb)
{
    __shared__ unsigned short Ss[GRP][32 * 56];
    __shared__ int sdone;

    const int t = threadIdx.x;
    const int g = blockIdx.x, lt = blockIdx.y;
    const int l0 = lt * 32;
    const int w = t >> 6, lane = t & 63, n_ = lane & 15, quad = lane >> 4;
    const int lh = (w >> 1) * 16, th = (w & 1) * 16;

    short8 qf[4];
    {
        const unsigned short* qrow = &Qp[(size_t)(l0 + lh + n_) * 128 + quad * 8];
#pragma unroll
        for (int kc = 0; kc < 4; kc++) qf[kc] = *(const short8*)(qrow + kc * 32);
    }

    f32x4 acc[2][8];
#pragma unroll
    for (int i = 0; i < 2; i++)
#pragma unroll
        for (int j = 0; j < 8; j++) acc[i][j] = (f32x4){0.f, 0.f, 0.f, 0.f};

    for (int ta = g; ta <= lt; ta += GRP * ng) {
#pragma unroll
        for (int p = 0; p < GRP; p++) {
            const int tile = ta + p * ng;
            if (tile > lt) continue;
            const int t0 = tile * 32;
            const unsigned short* krow = &Kp[(size_t)(t0 + th + n_) * 128 + quad * 8];
            f32x4 s = (f32x4){0.f, 0.f, 0.f, 0.f};
#pragma unroll
            for (int kc = 0; kc < 4; kc++)
                s = MFMA(qf[kc], *(const short8*)(krow + kc * 32), s);
            const int lrow = lh + quad * 4;
            if (tile == lt) {
                const int tg = t0 + th + n_;
#pragma unroll
                for (int reg = 0; reg < 4; reg++) {
                    float v = (tg <= l0 + lrow + reg) ? s[reg] : 0.f;
                    Ss[p][(lrow + reg) * 56 + th + n_] = f2bf(v);
                }
            } else {
#pragma unroll
                for (int reg = 0; reg < 4; reg++)
                    Ss[p][(lrow + reg) * 56 + th + n_] = f2bf(s[reg]);
            }
        }
        __syncthreads();
#pragma unroll
        for (int p = 0; p < GRP; p++) {
            const int tile = ta + p * ng;
            if (tile > lt) continue;
            const int t0 = tile * 32;
            short8 sa0 = *(const short8*)&Ss[p][n_ * 56 + quad * 8];
            short8 sa1 = *(const short8*)&Ss[p][(16 + n_) * 56 + quad * 8];
            const unsigned short* vrow = &Vt[(size_t)(w * 128 + n_) * 2048 + t0 + quad * 8];
#pragma unroll
            for (int jc = 0; jc < 8; jc++) {
                short8 vf = *(const short8*)(vrow + (size_t)jc * 16 * 2048);
                acc[0][jc] = MFMA(sa0, vf, acc[0][jc]);
                acc[1][jc] = MFMA(sa1, vf, acc[1][jc]);
            }
        }
        __syncthreads();
    }

    unsigned short* Pg = &P[((size_t)g * L_ + l0) * 512];
#pragma unroll
    for (int i = 0; i < 2; i++) {
#pragma unroll
        for (int jc = 0; jc < 8; jc++) {
            const int row = i * 16 + quad * 4;
            const int d = w * 128 + jc * 16 + n_;
#pragma unroll
            for (int reg = 0; reg < 4; reg++)
                Pg[(size_t)(row + reg) * 512 + d] = f2bf(acc[i][jc][reg]);
        }
    }

    // last block for this lt reduces + LayerNorms rows l0..l0+31
    __threadfence();
    if (t == 0) sdone = atomicAdd(&cnt[lt], 1);
    __syncthreads();
    if (sdone == ng - 1) {
        __threadfence();
        for (int rr = w; rr < 32; rr += 4) {
            const int l = l0 + rr;
            float v[8];
#pragma unroll
            for (int j = 0; j < 8; j++) v[j] = 0.f;
            for (int gi = 0; gi < ng; gi++) {
                us8 pk = *(const us8*)&P[((size_t)gi * L_ + l) * 512 + lane * 8];
#pragma unroll
                for (int j = 0; j < 8; j++) v[j] += bf2f((unsigned int)pk[j]);
            }
            const float scale = rsqrtf((float)((l + 1) * K_));
            float s = 0.f, s2 = 0.f;
#pragma unroll
            for (int j = 0; j < 8; j++) {
                v[j] *= scale;
                s += v[j]; s2 += v[j] * v[j];
            }
#pragma unroll
            for (int o = 32; o > 0; o >>= 1) {
                s  += __shfl_xor(s,  o);
                s2 += __shfl_xor(s2, o);
            }
            const float mu   = s * (1.f / 512.f);
            const float var  = s2 * (1.f / 512.f) - mu * mu;
            const float rstd = rsqrtf(var + 1e-5f);
#pragma unroll
            for (int j = 0; j < 8; j++) {
                const int d = lane * 8 + j;
                rnb[(size_t)l * 512 + d] = f2bf((v[j] - mu) * rstd * lng[d] + lnb[d]);
            }
        }
    }
}

// ---------- final out GEMM; bid = n*32 + m (XCD A-locality) ----------
__global__ __launch_bounds__(256)
void outg_k(const unsigned short* __restrict__ rnb, const unsigned short* wtout,
            const float* out_b, const float* __restrict__ x, float* __restrict__ out)
{
    __shared__ unsigned short As[2 * 4608];
    __shared__ unsigned short Bs[2 * 4608];
    const int wi = blockIdx.x;
    const int m0 = (wi & 31) * 64, n0 = (wi >> 5) * 64;
    gemm_body<EPI_OUT>(rnb, wtout, out_b, 512, 512, m0, n0, nullptr, out, x, As, Bs);
}

extern "C" void kernel_launch(void* const* d_in, const int* in_sizes, int n_in,
                              void* d_out, int out_size, void* d_ws, size_t ws_size,
                              hipStream_t stream)
{
    const float* x     = (const float*)d_in[0];
    const float* ke_w1 = (const float*)d_in[1];
    const float* ke_b1 = (const float*)d_in[2];
    const float* ke_w2 = (const float*)d_in[3];
    const float* ke_b2 = (const float*)d_in[4];
    const float* qe_w1 = (const float*)d_in[5];
    const float* qe_b1 = (const float*)d_in[6];
    const float* qe_w2 = (const float*)d_in[7];
    const float* qe_b2 = (const float*)d_in[8];
    const float* amp_w = (const float*)d_in[9];
    const float* amp_b = (const float*)d_in[10];
    const float* v_w   = (const float*)d_in[11];
    const float* v_b   = (const float*)d_in[12];
    const float* ln_g  = (const float*)d_in[13];
    const float* ln_b  = (const float*)d_in[14];
    const float* out_w = (const float*)d_in[15];
    const float* out_b = (const float*)d_in[16];
    float* out = (float*)d_out;
    char*  wsb = (char*)d_ws;

    unsigned short* xb    = (unsigned short*)(wsb + 0);          // 2 MB
    unsigned short* hk    = (unsigned short*)(wsb + 2097152);    // 2 MB
    unsigned short* hq    = (unsigned short*)(wsb + 4194304);    // 2 MB
    unsigned short* Vb    = (unsigned short*)(wsb + 6291456);    // 2 MB
    unsigned short* Vt    = (unsigned short*)(wsb + 8388608);    // 2 MB
    unsigned short* Qp    = (unsigned short*)(wsb + 10485760);   // 0.5 MB
    unsigned short* Kp    = (unsigned short*)(wsb + 11010048);   // 0.5 MB
    float*          amp   = (float*)(wsb + 11534336);            // 0.5 MB
    unsigned short* rnb   = (unsigned short*)(wsb + 12058624);   // 2 MB
    unsigned short* wtke1 = (unsigned short*)(wsb + 14155776);
    unsigned short* wtqe1 = (unsigned short*)(wsb + 14680064);
    unsigned short* wtv   = (unsigned short*)(wsb + 15204352);
    unsigned short* wtout = (unsigned short*)(wsb + 15728640);
    unsigned short* wtke2 = (unsigned short*)(wsb + 16252928);
    unsigned short* wtqe2 = (unsigned short*)(wsb + 16318464);
    unsigned short* wtamp = (unsigned short*)(wsb + 16384000);
    int*            cnt   = (int*)(wsb + 16449536);              // 256 B
    unsigned short* P     = (unsigned short*)(wsb + 16449792);   // ng * 2 MB (bf16)

    const size_t base_bytes = 16449792ull;
    const size_t per_group  = 2097152ull;
    int ng = 1;
    if (ws_size > base_bytes + per_group) {
        size_t n = (ws_size - base_bytes) / per_group;
        ng = (n > 8) ? 8 : (int)n;
        if (ng < 1) ng = 1;
    }

    dim3 blk(256);
    prep_k<<<dim3(16, 16, 8), blk, 0, stream>>>(x, xb, cnt,
                                                ke_w1, qe_w1, v_w, out_w, ke_w2, qe_w2, amp_w,
                                                wtke1, wtqe1, wtv, wtout, wtke2, wtqe2, wtamp);
    qkva_k<<<dim3(800), blk, 0, stream>>>(xb, wtke1, wtqe1, wtv, wtamp,
                                          ke_b1, qe_b1, v_b, amp_b, hk, hq, Vb, amp);
    phtv_k<<<dim3(1152), blk, 0, stream>>>(hk, hq, wtke2, wtqe2, ke_b2, qe_b2, amp,
                                           Kp, Qp, Vb, Vt);
    attm_k<<<dim3(ng, 64), blk, 0, stream>>>(Qp, Kp, Vt, P, ng, cnt, ln_g, ln_b, rnb);
    outg_k<<<dim3(256), blk, 0, stream>>>(rnb, wtout, out_b, x, out);
}

// Round 5
// 150.544 us; speedup vs baseline: 1.7972x; 1.7972x over previous
//
#include <hip/hip_runtime.h>
#include <math.h>

#define L_ 2048
#define D_ 512
#define K_ 64

typedef __attribute__((ext_vector_type(8))) short short8;
typedef __attribute__((ext_vector_type(4))) float f32x4;
typedef __attribute__((ext_vector_type(4))) unsigned short us4;

__device__ __forceinline__ unsigned short f2bf(float f) {
    unsigned int u = __builtin_bit_cast(unsigned int, f);
    u += 0x7fffu + ((u >> 16) & 1u);   // RNE
    return (unsigned short)(u >> 16);
}
__device__ __forceinline__ float bf2f(unsigned int u) {
    return __builtin_bit_cast(float, u << 16);
}
__device__ __forceinline__ f32x4 MFMA(short8 a, short8 b, f32x4 c) {
    return __builtin_amdgcn_mfma_f32_16x16x32_bf16(a, b, c, 0, 0, 0);
}

enum { EPI_BIAS = 0, EPI_GELU = 1, EPI_AMP = 2, EPI_OUT = 4 };

// ---------- pipelined bf16 MFMA GEMM body: 64x64 tile, BK=64, dbuf LDS ----------
template<int EPI>
__device__ __forceinline__ void gemm_body(
    const unsigned short* __restrict__ A, const unsigned short* __restrict__ Bt,
    const float* __restrict__ bias, int N, int Kd, int m0, int n0,
    unsigned short* __restrict__ Cb, float* __restrict__ Cf,
    const float* __restrict__ extra,
    unsigned short* As, unsigned short* Bs)      // each 2*64*72
{
    const int t = threadIdx.x;
    const int w = t >> 6, lane = t & 63, n_ = lane & 15, quad = lane >> 4;
    const int mh = (w >> 1) * 32, nh = (w & 1) * 32;

    f32x4 acc[2][2];
#pragma unroll
    for (int i = 0; i < 2; i++)
#pragma unroll
        for (int j = 0; j < 2; j++) acc[i][j] = (f32x4){0.f, 0.f, 0.f, 0.f};

    const int sr = t >> 2, sseg = (t & 3) * 16;
    const unsigned short* Ap = &A[(size_t)(m0 + sr) * Kd + sseg];
    const unsigned short* Bp = &Bt[(size_t)(n0 + sr) * Kd + sseg];
    const int swoff = sr * 72 + sseg;

    short8 av0 = *(const short8*)(Ap);
    short8 av1 = *(const short8*)(Ap + 8);
    short8 bv0 = *(const short8*)(Bp);
    short8 bv1 = *(const short8*)(Bp + 8);

    int buf = 0;
    *(short8*)(As + swoff) = av0; *(short8*)(As + swoff + 8) = av1;
    *(short8*)(Bs + swoff) = bv0; *(short8*)(Bs + swoff + 8) = bv1;
    __syncthreads();

    for (int k0 = 0; k0 < Kd; k0 += 64) {
        const bool more = (k0 + 64 < Kd);
        if (more) {
            av0 = *(const short8*)(Ap + k0 + 64);
            av1 = *(const short8*)(Ap + k0 + 72);
            bv0 = *(const short8*)(Bp + k0 + 64);
            bv1 = *(const short8*)(Bp + k0 + 72);
        }
        const unsigned short* Ab = As + buf * 4608;
        const unsigned short* Bb = Bs + buf * 4608;
#pragma unroll
        for (int kc = 0; kc < 2; kc++) {
            short8 a0 = *(const short8*)&Ab[(mh      + n_) * 72 + kc * 32 + quad * 8];
            short8 a1 = *(const short8*)&Ab[(mh + 16 + n_) * 72 + kc * 32 + quad * 8];
            short8 b0 = *(const short8*)&Bb[(nh      + n_) * 72 + kc * 32 + quad * 8];
            short8 b1 = *(const short8*)&Bb[(nh + 16 + n_) * 72 + kc * 32 + quad * 8];
            acc[0][0] = MFMA(a0, b0, acc[0][0]);
            acc[0][1] = MFMA(a0, b1, acc[0][1]);
            acc[1][0] = MFMA(a1, b0, acc[1][0]);
            acc[1][1] = MFMA(a1, b1, acc[1][1]);
        }
        if (more) {
            buf ^= 1;
            unsigned short* Aw = As + buf * 4608 + swoff;
            unsigned short* Bw = Bs + buf * 4608 + swoff;
            *(short8*)Aw = av0; *(short8*)(Aw + 8) = av1;
            *(short8*)Bw = bv0; *(short8*)(Bw + 8) = bv1;
            __syncthreads();
        }
    }

#pragma unroll
    for (int i = 0; i < 2; i++) {
#pragma unroll
        for (int j = 0; j < 2; j++) {
            const int mb = m0 + mh + i * 16 + quad * 4;
            const int nb = n0 + nh + j * 16 + n_;
            const float bsv = bias[nb];
#pragma unroll
            for (int reg = 0; reg < 4; reg++) {
                const int m = mb + reg;
                float v = acc[i][j][reg] + bsv;
                if (EPI == EPI_GELU) {
                    v = 0.5f * v * (1.0f + erff(v * 0.70710678118654752f));
                    Cb[(size_t)m * N + nb] = f2bf(v);
                } else if (EPI == EPI_BIAS) {
                    Cb[(size_t)m * N + nb] = f2bf(v);
                } else if (EPI == EPI_AMP) {
                    float u = (v > 20.f) ? v : log1pf(expf(v));
                    Cf[(size_t)m * N + nb] = u + 0.1f;
                } else { // EPI_OUT
                    Cf[(size_t)m * N + nb] = v + extra[(size_t)m * N + nb];
                }
            }
        }
    }
}

// ---------- phase GEMM body: 32x64 tile (N=64, Kd=512), dbuf, phase epilogue ----------
__device__ __forceinline__ void phase_body(
    const unsigned short* __restrict__ A, const unsigned short* __restrict__ Bt,
    const float* __restrict__ bias, int m0,
    unsigned short* __restrict__ Cb, const float* __restrict__ amp,
    unsigned short* As, unsigned short* Bs)   // As: 2*2304, Bs: 2*4608
{
    const int t = threadIdx.x;
    const int w = t >> 6, lane = t & 63, n_ = lane & 15, quad = lane >> 4;
    const int Kd = 512;

    f32x4 acc[2];
    acc[0] = (f32x4){0.f, 0.f, 0.f, 0.f};
    acc[1] = (f32x4){0.f, 0.f, 0.f, 0.f};

    const int arow = t >> 3, aseg = (t & 7) * 8;      // A: 32x64
    const int brow = t >> 2, bseg = (t & 3) * 16;     // B: 64x64
    const unsigned short* Ap = &A[(size_t)(m0 + arow) * Kd + aseg];
    const unsigned short* Bp = &Bt[(size_t)brow * Kd + bseg];
    const int aoff = arow * 72 + aseg;
    const int boff = brow * 72 + bseg;

    short8 av  = *(const short8*)Ap;
    short8 bv0 = *(const short8*)Bp;
    short8 bv1 = *(const short8*)(Bp + 8);

    int buf = 0;
    *(short8*)(As + aoff) = av;
    *(short8*)(Bs + boff) = bv0; *(short8*)(Bs + boff + 8) = bv1;
    __syncthreads();

    for (int k0 = 0; k0 < Kd; k0 += 64) {
        const bool more = (k0 + 64 < Kd);
        if (more) {
            av  = *(const short8*)(Ap + k0 + 64);
            bv0 = *(const short8*)(Bp + k0 + 64);
            bv1 = *(const short8*)(Bp + k0 + 72);
        }
        const unsigned short* Ab = As + buf * 2304;
        const unsigned short* Bb = Bs + buf * 4608;
#pragma unroll
        for (int kc = 0; kc < 2; kc++) {
            short8 a0 = *(const short8*)&Ab[(n_)      * 72 + kc * 32 + quad * 8];
            short8 a1 = *(const short8*)&Ab[(16 + n_) * 72 + kc * 32 + quad * 8];
            short8 b0 = *(const short8*)&Bb[(w * 16 + n_) * 72 + kc * 32 + quad * 8];
            acc[0] = MFMA(a0, b0, acc[0]);
            acc[1] = MFMA(a1, b0, acc[1]);
        }
        if (more) {
            buf ^= 1;
            *(short8*)(As + buf * 2304 + aoff) = av;
            *(short8*)(Bs + buf * 4608 + boff) = bv0;
            *(short8*)(Bs + buf * 4608 + boff + 8) = bv1;
            __syncthreads();
        }
    }

    const int nb = w * 16 + n_;
    const float bsv = bias[nb];
#pragma unroll
    for (int i = 0; i < 2; i++) {
        const int mb = m0 + i * 16 + quad * 4;
#pragma unroll
        for (int reg = 0; reg < 4; reg++) {
            const int m = mb + reg;
            float v = acc[i][reg] + bsv;
            float am = amp[(size_t)m * 64 + nb];
            float p = tanhf(v) * 3.14159265358979323846f;
            float sp, cp; sincosf(p, &sp, &cp);
            Cb[(size_t)m * 128 + nb]      = f2bf(am * cp);
            Cb[(size_t)m * 128 + 64 + nb] = f2bf(am * sp);
        }
    }
}

// ---------- prep: weight transpose+cast (z<7), x cast (z=7) ----------
__global__ __launch_bounds__(256)
void prep_k(const float* x, unsigned short* xb,
            const float* s0, const float* s1, const float* s2, const float* s3,
            const float* s4, const float* s5, const float* s6,
            unsigned short* d0, unsigned short* d1, unsigned short* d2, unsigned short* d3,
            unsigned short* d4, unsigned short* d5, unsigned short* d6)
{
    const int t = threadIdx.x;
    if (blockIdx.z == 7) {
        const int b = blockIdx.y * 16 + blockIdx.x;       // 0..255
        const float4* src = (const float4*)x;
#pragma unroll
        for (int j = 0; j < 4; j++) {
            const int idx = b * 1024 + j * 256 + t;
            float4 v = src[idx];
            us4 o;
            o.x = f2bf(v.x); o.y = f2bf(v.y); o.z = f2bf(v.z); o.w = f2bf(v.w);
            *(us4*)&xb[(size_t)idx * 4] = o;
        }
        return;
    }
    const float* S; unsigned short* D; int C;
    switch (blockIdx.z) {
        case 0: S = s0; D = d0; C = 512; break;
        case 1: S = s1; D = d1; C = 512; break;
        case 2: S = s2; D = d2; C = 512; break;
        case 3: S = s3; D = d3; C = 512; break;
        case 4: S = s4; D = d4; C = 64;  break;
        case 5: S = s5; D = d5; C = 64;  break;
        default: S = s6; D = d6; C = 64; break;
    }
    const int R = 512;
    int c0 = blockIdx.x * 32, r0 = blockIdx.y * 32;
    if (c0 >= C) return;
    __shared__ float tile[32][33];
    int r = t >> 3, c4 = (t & 7) * 4;
    float4 v = *(const float4*)&S[(size_t)(r0 + r) * C + c0 + c4];
    tile[r][c4 + 0] = v.x; tile[r][c4 + 1] = v.y;
    tile[r][c4 + 2] = v.z; tile[r][c4 + 3] = v.w;
    __syncthreads();
    us4 o;
    o.x = f2bf(tile[c4 + 0][r]); o.y = f2bf(tile[c4 + 1][r]);
    o.z = f2bf(tile[c4 + 2][r]); o.w = f2bf(tile[c4 + 3][r]);
    *(us4*)&D[(size_t)(c0 + r) * R + r0 + c4] = o;
}

// ---------- fused ke1+qe1+v+amp GEMMs; bid = which*256 + n*32 + m  (XCD A-locality) ----
__global__ __launch_bounds__(256)
void qkva_k(const unsigned short* __restrict__ xb,
            const unsigned short* wtke1, const unsigned short* wtqe1,
            const unsigned short* wtv, const unsigned short* wtamp,
            const float* ke_b1, const float* qe_b1, const float* v_b, const float* amp_b,
            unsigned short* hk, unsigned short* hq, unsigned short* Vb, float* amp)
{
    __shared__ unsigned short As[2 * 4608];
    __shared__ unsigned short Bs[2 * 4608];
    const int b = blockIdx.x;
    if (b < 768) {
        const int which = b >> 8, wi = b & 255;
        const int m0 = (wi & 31) * 64, n0 = (wi >> 5) * 64;
        if (which == 0)
            gemm_body<EPI_GELU>(xb, wtke1, ke_b1, 512, 512, m0, n0, hk, nullptr, nullptr, As, Bs);
        else if (which == 1)
            gemm_body<EPI_GELU>(xb, wtqe1, qe_b1, 512, 512, m0, n0, hq, nullptr, nullptr, As, Bs);
        else
            gemm_body<EPI_BIAS>(xb, wtv, v_b, 512, 512, m0, n0, Vb, nullptr, nullptr, As, Bs);
    } else {
        const int m0 = (b - 768) * 64;
        gemm_body<EPI_AMP>(xb, wtamp, amp_b, 64, 512, m0, 0, nullptr, amp, nullptr, As, Bs);
    }
}

// ---------- fused phase GEMMs (128 blocks of 32x64) + V transpose ----------
__global__ __launch_bounds__(256)
void phtv_k(const unsigned short* __restrict__ hk, const unsigned short* __restrict__ hq,
            const unsigned short* wtke2, const unsigned short* wtqe2,
            const float* ke_b2, const float* qe_b2, const float* ampv,
            unsigned short* Kp, unsigned short* Qp,
            const unsigned short* __restrict__ Vb, unsigned short* __restrict__ Vt)
{
    __shared__ unsigned short As[2 * 2304];
    __shared__ unsigned short Bs[2 * 4608];
    const int b = blockIdx.x;
    if (b < 128) {
        if (b < 64)
            phase_body(hk, wtke2, ke_b2, b * 32, Kp, ampv, As, Bs);
        else
            phase_body(hq, wtqe2, qe_b2, (b - 64) * 32, Qp, ampv, As, Bs);
    } else {
        const int bb = b - 128;
        const int c0 = (bb & 15) * 32, r0 = (bb >> 4) * 32;
        unsigned short (*tile)[33] = (unsigned short (*)[33])As;
        const int t = threadIdx.x, r = t >> 3, c4 = (t & 7) * 4;
        us4 v = *(const us4*)&Vb[(size_t)(r0 + r) * 512 + c0 + c4];
        tile[r][c4 + 0] = v.x; tile[r][c4 + 1] = v.y;
        tile[r][c4 + 2] = v.z; tile[r][c4 + 3] = v.w;
        __syncthreads();
        us4 o;
        o.x = tile[c4 + 0][r]; o.y = tile[c4 + 1][r];
        o.z = tile[c4 + 2][r]; o.w = tile[c4 + 3][r];
        *(us4*)&Vt[(size_t)(c0 + r) * 2048 + r0 + c4] = o;
    }
}

// ---------- MFMA causal attention, bf16 partials (r3-proven form, VGPR 132) ----------
__global__ __launch_bounds__(256)
void attm_k(const unsigned short* __restrict__ Qp, const unsigned short* __restrict__ Kp,
            const unsigned short* __restrict__ Vt, unsigned short* __restrict__ P, int ng)
{
    __shared__ unsigned short Ss[32 * 56];

    const int t = threadIdx.x;
    const int g = blockIdx.x, lt = blockIdx.y;
    const int l0 = lt * 32;
    const int w = t >> 6, lane = t & 63, n_ = lane & 15, quad = lane >> 4;
    const int lh = (w >> 1) * 16, th = (w & 1) * 16;

    short8 qf[4];
    {
        const unsigned short* qrow = &Qp[(size_t)(l0 + lh + n_) * 128 + quad * 8];
#pragma unroll
        for (int kc = 0; kc < 4; kc++) qf[kc] = *(const short8*)(qrow + kc * 32);
    }

    f32x4 acc[2][8];
#pragma unroll
    for (int i = 0; i < 2; i++)
#pragma unroll
        for (int j = 0; j < 8; j++) acc[i][j] = (f32x4){0.f, 0.f, 0.f, 0.f};

    for (int tile = g; tile <= lt; tile += ng) {
        const int t0 = tile * 32;
        const unsigned short* krow = &Kp[(size_t)(t0 + th + n_) * 128 + quad * 8];
        f32x4 s = (f32x4){0.f, 0.f, 0.f, 0.f};
#pragma unroll
        for (int kc = 0; kc < 4; kc++)
            s = MFMA(qf[kc], *(const short8*)(krow + kc * 32), s);

        const int lrow = lh + quad * 4;
        if (tile == lt) {
            const int tg = t0 + th + n_;
#pragma unroll
            for (int reg = 0; reg < 4; reg++) {
                float v = (tg <= l0 + lrow + reg) ? s[reg] : 0.f;
                Ss[(lrow + reg) * 56 + th + n_] = f2bf(v);
            }
        } else {
#pragma unroll
            for (int reg = 0; reg < 4; reg++)
                Ss[(lrow + reg) * 56 + th + n_] = f2bf(s[reg]);
        }
        __syncthreads();

        short8 sa0 = *(const short8*)&Ss[n_ * 56 + quad * 8];
        short8 sa1 = *(const short8*)&Ss[(16 + n_) * 56 + quad * 8];
        const unsigned short* vrow = &Vt[(size_t)(w * 128 + n_) * 2048 + t0 + quad * 8];
#pragma unroll
        for (int jc = 0; jc < 8; jc++) {
            short8 vf = *(const short8*)(vrow + (size_t)jc * 16 * 2048);
            acc[0][jc] = MFMA(sa0, vf, acc[0][jc]);
            acc[1][jc] = MFMA(sa1, vf, acc[1][jc]);
        }
        __syncthreads();
    }

    unsigned short* Pg = &P[((size_t)g * L_ + l0) * 512];
#pragma unroll
    for (int i = 0; i < 2; i++) {
#pragma unroll
        for (int jc = 0; jc < 8; jc++) {
            const int row = i * 16 + quad * 4;
            const int d = w * 128 + jc * 16 + n_;
#pragma unroll
            for (int reg = 0; reg < 4; reg++)
                Pg[(size_t)(row + reg) * 512 + d] = f2bf(acc[i][jc][reg]);
        }
    }
}

// ---------- reduce partials (bf16), scale, LayerNorm -> rn (bf16) ----------
__global__ __launch_bounds__(256)
void redln_k(const unsigned short* __restrict__ P, int ng,
             const float* __restrict__ lng, const float* __restrict__ lnb,
             unsigned short* __restrict__ rnb)
{
    const int l = blockIdx.x, t = threadIdx.x;
    float rx = 0.f, ry = 0.f;
    for (int gi = 0; gi < ng; gi++) {
        unsigned int p = *(const unsigned int*)&P[((size_t)gi * L_ + l) * 512 + 2 * t];
        rx += bf2f(p & 0xffffu);
        ry += bf2f(p >> 16);
    }
    const float scale = rsqrtf((float)((l + 1) * K_));
    rx *= scale; ry *= scale;

    float s = rx + ry, s2 = rx * rx + ry * ry;
    __shared__ float sb[8];
#pragma unroll
    for (int o = 32; o > 0; o >>= 1) {
        s  += __shfl_down(s,  o);
        s2 += __shfl_down(s2, o);
    }
    if ((t & 63) == 0) { int wv = t >> 6; sb[wv] = s; sb[4 + wv] = s2; }
    __syncthreads();
    s  = sb[0] + sb[1] + sb[2] + sb[3];
    s2 = sb[4] + sb[5] + sb[6] + sb[7];

    const float mu   = s * (1.f / 512.f);
    const float var  = s2 * (1.f / 512.f) - mu * mu;
    const float rstd = rsqrtf(var + 1e-5f);

    const int d = t << 1;
    rnb[(size_t)l * 512 + d]     = f2bf((rx - mu) * rstd * lng[d]     + lnb[d]);
    rnb[(size_t)l * 512 + d + 1] = f2bf((ry - mu) * rstd * lng[d + 1] + lnb[d + 1]);
}

// ---------- final out GEMM; bid = n*32 + m (XCD A-locality) ----------
__global__ __launch_bounds__(256)
void outg_k(const unsigned short* __restrict__ rnb, const unsigned short* wtout,
            const float* out_b, const float* __restrict__ x, float* __restrict__ out)
{
    __shared__ unsigned short As[2 * 4608];
    __shared__ unsigned short Bs[2 * 4608];
    const int wi = blockIdx.x;
    const int m0 = (wi & 31) * 64, n0 = (wi >> 5) * 64;
    gemm_body<EPI_OUT>(rnb, wtout, out_b, 512, 512, m0, n0, nullptr, out, x, As, Bs);
}

extern "C" void kernel_launch(void* const* d_in, const int* in_sizes, int n_in,
                              void* d_out, int out_size, void* d_ws, size_t ws_size,
                              hipStream_t stream)
{
    const float* x     = (const float*)d_in[0];
    const float* ke_w1 = (const float*)d_in[1];
    const float* ke_b1 = (const float*)d_in[2];
    const float* ke_w2 = (const float*)d_in[3];
    const float* ke_b2 = (const float*)d_in[4];
    const float* qe_w1 = (const float*)d_in[5];
    const float* qe_b1 = (const float*)d_in[6];
    const float* qe_w2 = (const float*)d_in[7];
    const float* qe_b2 = (const float*)d_in[8];
    const float* amp_w = (const float*)d_in[9];
    const float* amp_b = (const float*)d_in[10];
    const float* v_w   = (const float*)d_in[11];
    const float* v_b   = (const float*)d_in[12];
    const float* ln_g  = (const float*)d_in[13];
    const float* ln_b  = (const float*)d_in[14];
    const float* out_w = (const float*)d_in[15];
    const float* out_b = (const float*)d_in[16];
    float* out = (float*)d_out;
    char*  wsb = (char*)d_ws;

    unsigned short* xb    = (unsigned short*)(wsb + 0);          // 2 MB
    unsigned short* hk    = (unsigned short*)(wsb + 2097152);    // 2 MB
    unsigned short* hq    = (unsigned short*)(wsb + 4194304);    // 2 MB
    unsigned short* Vb    = (unsigned short*)(wsb + 6291456);    // 2 MB
    unsigned short* Vt    = (unsigned short*)(wsb + 8388608);    // 2 MB
    unsigned short* Qp    = (unsigned short*)(wsb + 10485760);   // 0.5 MB
    unsigned short* Kp    = (unsigned short*)(wsb + 11010048);   // 0.5 MB
    float*          amp   = (float*)(wsb + 11534336);            // 0.5 MB
    unsigned short* rnb   = (unsigned short*)(wsb + 12058624);   // 2 MB
    unsigned short* wtke1 = (unsigned short*)(wsb + 14155776);
    unsigned short* wtqe1 = (unsigned short*)(wsb + 14680064);
    unsigned short* wtv   = (unsigned short*)(wsb + 15204352);
    unsigned short* wtout = (unsigned short*)(wsb + 15728640);
    unsigned short* wtke2 = (unsigned short*)(wsb + 16252928);
    unsigned short* wtqe2 = (unsigned short*)(wsb + 16318464);
    unsigned short* wtamp = (unsigned short*)(wsb + 16384000);
    unsigned short* P     = (unsigned short*)(wsb + 16449536);   // ng * 2 MB (bf16)

    const size_t base_bytes = 16449536ull;
    const size_t per_group  = 2097152ull;
    int ng = 1;
    if (ws_size > base_bytes + per_group) {
        size_t n = (ws_size - base_bytes) / per_group;
        ng = (n > 8) ? 8 : (int)n;
        if (ng < 1) ng = 1;
    }

    dim3 blk(256);
    prep_k<<<dim3(16, 16, 8), blk, 0, stream>>>(x, xb,
                                                ke_w1, qe_w1, v_w, out_w, ke_w2, qe_w2, amp_w,
                                                wtke1, wtqe1, wtv, wtout, wtke2, wtqe2, wtamp);
    qkva_k<<<dim3(800), blk, 0, stream>>>(xb, wtke1, wtqe1, wtv, wtamp,
                                          ke_b1, qe_b1, v_b, amp_b, hk, hq, Vb, amp);
    phtv_k<<<dim3(1152), blk, 0, stream>>>(hk, hq, wtke2, wtqe2, ke_b2, qe_b2, amp,
                                           Kp, Qp, Vb, Vt);
    attm_k<<<dim3(ng, 64), blk, 0, stream>>>(Qp, Kp, Vt, P, ng);
    redln_k<<<dim3(L_), blk, 0, stream>>>(P, ng, ln_g, ln_b, rnb);
    outg_k<<<dim3(256), blk, 0, stream>>>(rnb, wtout, out_b, x, out);
}